// Round 1
// baseline (8515.070 us; speedup 1.0000x reference)
//
#include <hip/hip_runtime.h>

#define B_  256
#define T_  512
#define IN_ 34
#define H_  80
#define L_  10
#define NC_ 5
#define G4  320   // 4*H

__device__ __forceinline__ float sigm(float x)     { return 1.f / (1.f + __expf(-x)); }
__device__ __forceinline__ float tanhfast(float x) { return 1.f - 2.f / (__expf(2.f * x) + 1.f); }

// One LSTM layer scan for one batch row, executed by the whole 320-thread block.
// Thread g owns gate row g (weights in registers). xs/hs/gsh are LDS.
template <int K, bool FIRST, bool LAST>
__device__ __forceinline__ void layer_scan(
    const float* __restrict__ WihRow,   // row g of W_ih for this layer (stride 34 or 80)
    const float* __restrict__ WhhRow,   // row g of W_hh for this layer (stride 80)
    float bias,                         // b_ih[g] + b_hh[g]
    const float* __restrict__ xin,      // FIRST: x + b*T*34 ; else hbuf + b*T*80
    float* __restrict__ hb,             // hbuf + b*T*80 (written unless LAST)
    float* xs, float* hs, float* gsh,
    int g)
{
    // Load this thread's weight rows into registers.
    float wih[K];
#pragma unroll
    for (int k = 0; k < K; ++k)
        wih[k] = (FIRST && k >= IN_) ? 0.f : WihRow[k];

    float whh[H_];
#pragma unroll
    for (int k = 0; k < H_; ++k)
        whh[k] = WhhRow[k];

    float c = 0.f;
    if (g < H_) hs[g] = 0.f;
    if (FIRST && g >= IN_ && g < K) xs[g] = 0.f;   // zero-pad once (never rewritten)
    __syncthreads();

    for (int t = 0; t < T_; ++t) {
        // Stage x_t into LDS.
        if (FIRST) { if (g < IN_) xs[g] = xin[t * IN_ + g]; }
        else       { if (g < H_)  xs[g] = xin[t * H_  + g]; }
        __syncthreads();   // barrier A: xs ready, hs(t) ready

        // gate pre-activation: dot over x (K) and h (80), 4 accumulators
        float a0 = bias, a1 = 0.f, a2 = 0.f, a3 = 0.f;
        const float4* xs4 = (const float4*)xs;
        const float4* hs4 = (const float4*)hs;
#pragma unroll
        for (int k = 0; k < K / 4; ++k) {
            float4 v = xs4[k];
            a0 += wih[4 * k + 0] * v.x;
            a1 += wih[4 * k + 1] * v.y;
            a2 += wih[4 * k + 2] * v.z;
            a3 += wih[4 * k + 3] * v.w;
        }
#pragma unroll
        for (int k = 0; k < H_ / 4; ++k) {
            float4 v = hs4[k];
            a0 += whh[4 * k + 0] * v.x;
            a1 += whh[4 * k + 1] * v.y;
            a2 += whh[4 * k + 2] * v.z;
            a3 += whh[4 * k + 3] * v.w;
        }
        gsh[g] = (a0 + a1) + (a2 + a3);
        __syncthreads();   // barrier B: all gates written, all dot-reads of xs/hs done

        if (g < H_) {
            float ig = sigm(gsh[g]);
            float fg = sigm(gsh[g + H_]);
            float gg = tanhfast(gsh[g + 2 * H_]);
            float og = sigm(gsh[g + 3 * H_]);
            c = fg * c + ig * gg;
            float h = og * tanhfast(c);
            hs[g] = h;                       // read only after next barrier A
            if (!LAST) hb[t * H_ + g] = h;   // in-place: this (b,t) already consumed
        }
    }
}

__global__ __launch_bounds__(320, 1) void lstm_stack_kernel(
    const float* __restrict__ x,     // [B,T,34]
    const float* __restrict__ Wih0,  // [320,34]
    const float* __restrict__ WihR,  // [9,320,80]
    const float* __restrict__ Whh,   // [10,320,80]
    const float* __restrict__ bih,   // [10,320]
    const float* __restrict__ bhh,   // [10,320]
    const float* __restrict__ fcw,   // [5,80]
    const float* __restrict__ fcb,   // [5]
    float* __restrict__ out,         // [B,5]
    float* __restrict__ hbuf)        // scratch [B,T,80]
{
    const int b = blockIdx.x;
    const int g = threadIdx.x;   // 0..319

    __shared__ __align__(16) float xs[80];
    __shared__ __align__(16) float hs[80];
    __shared__ float gsh[G4];

    float* hb = hbuf + (size_t)b * T_ * H_;

    // layer 0 (input dim 34, padded to 36 for /4 vectorization)
    layer_scan<36, true, false>(Wih0 + (size_t)g * IN_,
                                Whh + (size_t)g * H_,
                                bih[g] + bhh[g],
                                x + (size_t)b * T_ * IN_,
                                hb, xs, hs, gsh, g);
    __syncthreads();

    // layers 1..8
    for (int l = 1; l < L_ - 1; ++l) {
        layer_scan<80, false, false>(WihR + ((size_t)(l - 1) * G4 + g) * H_,
                                     Whh + ((size_t)l * G4 + g) * H_,
                                     bih[l * G4 + g] + bhh[l * G4 + g],
                                     hb, hb, xs, hs, gsh, g);
        __syncthreads();
    }

    // layer 9 (no h history needed; final h stays in LDS)
    layer_scan<80, false, true>(WihR + ((size_t)8 * G4 + g) * H_,
                                Whh + ((size_t)9 * G4 + g) * H_,
                                bih[9 * G4 + g] + bhh[9 * G4 + g],
                                hb, hb, xs, hs, gsh, g);
    __syncthreads();

    // fc on last timestep's hidden state
    if (g < NC_) {
        float acc = fcb[g];
#pragma unroll
        for (int j = 0; j < H_; ++j)
            acc += fcw[g * H_ + j] * hs[j];
        out[b * NC_ + g] = acc;
    }
}

extern "C" void kernel_launch(void* const* d_in, const int* in_sizes, int n_in,
                              void* d_out, int out_size, void* d_ws, size_t ws_size,
                              hipStream_t stream) {
    const float* x    = (const float*)d_in[0];
    const float* Wih0 = (const float*)d_in[1];
    const float* WihR = (const float*)d_in[2];
    const float* Whh  = (const float*)d_in[3];
    const float* bih  = (const float*)d_in[4];
    const float* bhh  = (const float*)d_in[5];
    const float* fcw  = (const float*)d_in[6];
    const float* fcb  = (const float*)d_in[7];

    float* out  = (float*)d_out;
    float* hbuf = (float*)d_ws;   // needs B*T*H*4 = 41.9 MB

    lstm_stack_kernel<<<dim3(B_), dim3(G4), 0, stream>>>(
        x, Wih0, WihR, Whh, bih, bhh, fcw, fcb, out, hbuf);
}